// Round 5
// baseline (464.819 us; speedup 1.0000x reference)
//
#include <hip/hip_runtime.h>
#include <stdint.h>

#define N_TOK 4096
#define C_DIM 256

typedef __attribute__((ext_vector_type(8))) short short8;
typedef __attribute__((ext_vector_type(8))) _Float16 half8;
typedef __attribute__((ext_vector_type(4))) float floatx4;
typedef __attribute__((ext_vector_type(16))) float floatx16;
typedef __attribute__((ext_vector_type(4))) unsigned short ushort4v;

__device__ __forceinline__ unsigned short bf16_rne(float f) {
    union { float f; unsigned int u; } v; v.f = f;
    unsigned int u = v.u;
    unsigned int rounded = u + 0x7FFFu + ((u >> 16) & 1u);
    return (unsigned short)(rounded >> 16);
}
__device__ __forceinline__ float bf16_to_f(unsigned short h) {
    union { unsigned int u; float f; } v; v.u = ((unsigned int)h) << 16;
    return v.f;
}
__device__ __forceinline__ void split_bf16(float f, unsigned short& h, unsigned short& l) {
    h = bf16_rne(f);
    l = bf16_rne(f - bf16_to_f(h));
}
__device__ __forceinline__ unsigned short f2h(float f) {
    union { _Float16 h; unsigned short u; } v; v.h = (_Float16)f; return v.u;
}
__device__ __forceinline__ float h2f(unsigned short u) {
    union { unsigned short u; _Float16 h; } v; v.u = u; return (float)v.h;
}
// pack two floats -> half2 (RNE)
__device__ __forceinline__ unsigned int pack2h(float a, float b) {
    union { _Float16 h[2]; unsigned int u; } v;
    v.h[0] = (_Float16)a; v.h[1] = (_Float16)b;
    return v.u;
}
// async global->LDS 16B/lane; LDS dest = wave-uniform base + lane*16
__device__ __forceinline__ void g2l16(const void* g, void* l) {
    __builtin_amdgcn_global_load_lds(
        (const __attribute__((address_space(1))) void*)g,
        (__attribute__((address_space(3))) void*)l, 16, 0, 0);
}

// ---------------------------------------------------------------------------
// prep_kernel: one-time split/transpose (bf16 hi/lo pairs for fp32-accurate
// projection GEMM).  (unchanged)
// ---------------------------------------------------------------------------
__global__ __launch_bounds__(256) void prep_kernel(
    const float* __restrict__ x,
    const float* __restrict__ Wq, const float* __restrict__ Wk, const float* __restrict__ Wv,
    unsigned short* __restrict__ Xhi, unsigned short* __restrict__ Xlo,
    unsigned short* __restrict__ Whi, unsigned short* __restrict__ Wlo)
{
    const int t = threadIdx.x;
    if (blockIdx.x >= 1024) {
        const int pj = blockIdx.x - 1024;
        const float* W = (pj == 0) ? Wq : (pj == 1) ? Wk : Wv;
        unsigned short* dh = Whi + pj * 65536;
        unsigned short* dl = Wlo + pj * 65536;
        for (int it = 0; it < 64; it++) {
            const int idx = it * 1024 + t * 4;
            const float4 w = *(const float4*)&W[idx];
            unsigned short h0, l0, h1, l1, h2, l2, h3, l3;
            split_bf16(w.x, h0, l0); split_bf16(w.y, h1, l1);
            split_bf16(w.z, h2, l2); split_bf16(w.w, h3, l3);
            ushort4v vh; vh[0] = h0; vh[1] = h1; vh[2] = h2; vh[3] = h3;
            ushort4v vl; vl[0] = l0; vl[1] = l1; vl[2] = l2; vl[3] = l3;
            *(ushort4v*)&dh[idx] = vh;
            *(ushort4v*)&dl[idx] = vl;
        }
        return;
    }
    __shared__ float Xs[64 * 65];   // pitch 65: conflict-free transpose
    const int b  = blockIdx.x >> 8;
    const int ct = (blockIdx.x >> 6) & 3;
    const int nt = blockIdx.x & 63;
    const int c0 = ct * 64, n0 = nt * 64;
    {
        const int nch = t & 15, cr = t >> 4;
#pragma unroll
        for (int pass = 0; pass < 4; pass++) {
            const int c = pass * 16 + cr;
            const float4 v = *(const float4*)&x[((size_t)(b * C_DIM + c0 + c)) * N_TOK + n0 + nch * 4];
            float* row = &Xs[c * 65 + nch * 4];
            row[0] = v.x; row[1] = v.y; row[2] = v.z; row[3] = v.w;
        }
    }
    __syncthreads();
    {
        const int n = t >> 2, cc = t & 3;
        short8 vh0, vl0, vh1, vl1;
#pragma unroll
        for (int i = 0; i < 8; i++) {
            unsigned short h, l;
            split_bf16(Xs[(cc * 16 + i) * 65 + n], h, l);
            vh0[i] = (short)h; vl0[i] = (short)l;
        }
#pragma unroll
        for (int i = 0; i < 8; i++) {
            unsigned short h, l;
            split_bf16(Xs[(cc * 16 + 8 + i) * 65 + n], h, l);
            vh1[i] = (short)h; vl1[i] = (short)l;
        }
        const size_t off = ((size_t)b * N_TOK + n0 + n) * C_DIM + c0 + cc * 16;
        *(short8*)&Xhi[off] = vh0; *(short8*)&Xhi[off + 8] = vh1;
        *(short8*)&Xlo[off] = vl0; *(short8*)&Xlo[off + 8] = vl1;
    }
}

// ---------------------------------------------------------------------------
// proj_kernel: Out[n,o] = sum_c x[n,c]*W[o,c] + bias (+pos for K').
// Q output is now SWIZZLED for the 32x32 flash B-frag loads:
//   Qh[b][qt=n>>7][phase=(o>>3)][q=n&127][i=o&7]   (phase = ct*2+H, 32 of them)
// so a flash wave's 64 lanes load two contiguous 512B runs per phase.
// ---------------------------------------------------------------------------
__global__ __launch_bounds__(256) void proj_kernel(
    const unsigned short* __restrict__ Xhi, const unsigned short* __restrict__ Xlo,
    const unsigned short* __restrict__ Whi, const unsigned short* __restrict__ Wlo,
    const float* __restrict__ bq, const float* __restrict__ bk, const float* __restrict__ bv,
    const float* __restrict__ relh, const float* __restrict__ relw,
    unsigned short* __restrict__ Qh,
    unsigned short* __restrict__ Kh,
    unsigned short* __restrict__ Vh)
{
    __shared__ unsigned short SM[20480];   // 40KB carve
    unsigned short* Ah = SM;               // [64][32]
    unsigned short* Al = SM + 2048;
    unsigned short* Bh = SM + 4096;        // [256][32]
    unsigned short* Bl = SM + 12288;

    const int t    = threadIdx.x;
    const int wave = t >> 6;
    const int lane = t & 63;
    const int l15  = lane & 15;
    const int quad = lane >> 4;

    const int bp   = blockIdx.x >> 6;
    const int proj = bp % 3;
    const int b    = bp / 3;
    const int n0   = (blockIdx.x & 63) * 64;

    const unsigned short* Xh = Xhi + ((size_t)b * N_TOK + n0) * C_DIM;
    const unsigned short* Xl = Xlo + ((size_t)b * N_TOK + n0) * C_DIM;
    const unsigned short* Wh = Whi + proj * 65536;
    const unsigned short* Wl = Wlo + proj * 65536;
    const float* bias = (proj == 0) ? bq : (proj == 1) ? bk : bv;
    const bool needlo = (proj < 2);

    floatx4 acc[16];
#pragma unroll
    for (int i = 0; i < 16; i++) acc[i] = (floatx4){0.f, 0.f, 0.f, 0.f};

    for (int c0 = 0; c0 < 256; c0 += 32) {
        {
            const int lr = lane >> 2, cp = lane & 3;
            const int key = (lr ^ (lr >> 2)) & 3;
            const int r = wave * 16 + lr;
            g2l16(Xh + (size_t)r * C_DIM + c0 + (cp ^ key) * 8, &Ah[wave * 512]);
            if (needlo) g2l16(Xl + (size_t)r * C_DIM + c0 + (cp ^ key) * 8, &Al[wave * 512]);
#pragma unroll
            for (int p = 0; p < 4; p++) {
                const int rb = (p * 4 + wave) * 16;
                const int rr = rb + lr;
                g2l16(Wh + (size_t)rr * 256 + c0 + (cp ^ key) * 8, &Bh[rb * 32]);
                if (needlo) g2l16(Wl + (size_t)rr * 256 + c0 + (cp ^ key) * 8, &Bl[rb * 32]);
            }
        }
        __syncthreads();

        const int akey = (l15 ^ (l15 >> 2)) & 3;
        const int arow = (wave * 16 + l15) * 32 + ((quad ^ akey) * 8);
        const short8 a_h = *(const short8*)&Ah[arow];
        short8 a_l;
        if (needlo) a_l = *(const short8*)&Al[arow];
#pragma unroll
        for (int ot = 0; ot < 16; ot++) {
            const int brow = (ot * 16 + l15) * 32 + ((quad ^ akey) * 8);
            const short8 b_h = *(const short8*)&Bh[brow];
            acc[ot] = __builtin_amdgcn_mfma_f32_16x16x32_bf16(a_h, b_h, acc[ot], 0, 0, 0);
            if (needlo) {
                const short8 b_l = *(const short8*)&Bl[brow];
                acc[ot] = __builtin_amdgcn_mfma_f32_16x16x32_bf16(a_l, b_h, acc[ot], 0, 0, 0);
                acc[ot] = __builtin_amdgcn_mfma_f32_16x16x32_bf16(a_h, b_l, acc[ot], 0, 0, 0);
            }
        }
        __syncthreads();
    }

    // ---- epilogue (all fp16 outputs) ----
    const int h0 = n0 >> 6;   // pos[c][n] = relh[c][n>>6] + relw[c][n&63]
    if (proj == 0) {
        // swizzled Q: [qt][phase=o>>3][q128][i=o&7]
        unsigned short* Og = Qh + (size_t)b * N_TOK * C_DIM;
#pragma unroll
        for (int ot = 0; ot < 16; ot++) {
            const int o = ot * 16 + l15;
            const float bs = bias[o];
            const int phase = o >> 3;       // = ot*2 + (l15>>3)
            const int ii    = o & 7;
#pragma unroll
            for (int r = 0; r < 4; r++) {
                const int n  = n0 + wave * 16 + quad * 4 + r;
                const int qt = n >> 7, q128 = n & 127;
                Og[(size_t)qt * 32768 + phase * 1024 + q128 * 8 + ii] = f2h(acc[ot][r] + bs);
            }
        }
    } else if (proj == 1) {
        unsigned short* Og = Kh + ((size_t)b * N_TOK + n0) * C_DIM;
#pragma unroll
        for (int ot = 0; ot < 16; ot++) {
            const int o = ot * 16 + l15;
            const float bs = bias[o];
            const float ph = relh[o * 64 + h0];
#pragma unroll
            for (int r = 0; r < 4; r++) {
                const int nl = wave * 16 + quad * 4 + r;
                Og[(size_t)nl * C_DIM + o] = f2h(acc[ot][r] + bs + ph + relw[o * 64 + nl]);
            }
        }
    } else {
        // V: fp16, transpose via LDS (reuse SM: 256x72 shorts = 36KB)
        unsigned short* Vt = SM;
#pragma unroll
        for (int ot = 0; ot < 16; ot++) {
            const int o = ot * 16 + l15;
            const float bs = bias[o];
            const unsigned int u0 = (unsigned int)f2h(acc[ot][0] + bs) |
                                    ((unsigned int)f2h(acc[ot][1] + bs) << 16);
            const unsigned int u1 = (unsigned int)f2h(acc[ot][2] + bs) |
                                    ((unsigned int)f2h(acc[ot][3] + bs) << 16);
            uint2 uv; uv.x = u0; uv.y = u1;
            *(uint2*)&Vt[o * 72 + wave * 16 + quad * 4] = uv;
        }
        __syncthreads();
        const int ch   = t & 7;
        const int orow = t >> 3;
#pragma unroll
        for (int pass = 0; pass < 8; pass++) {
            const int o = pass * 32 + orow;
            const short8 vv = *(const short8*)&Vt[o * 72 + ch * 8];
            *(short8*)&Vh[((size_t)b * C_DIM + o) * N_TOK + n0 + ch * 8] = vv;
        }
    }
}

// ---------------------------------------------------------------------------
// flash_kernel v7: 32x32x16 MFMAs (2x FLOP per ds_read_b128) with Q
// RE-LOADED from the swizzled global blob each S-phase instead of resident
// in 64 VGPRs.  Round-4 showed the (256,2) budget splits 128 arch + 128
// AGPR(oacc); resident qf blew the arch half -> scratch spill (1.2GB).
// Q tile (64KB/block) is L2-resident across its 16 re-reads; loads are
// fully coalesced (16B/lane, two 512B runs per wave) and interleave with
// the S-MFMAs.  All numerics identical to round-4's PASSING kernel.
// 256 thr / 4 waves, q=32/wave, NS=4, NITER=16, LDS 64KB, 2 blocks/CU.
// ---------------------------------------------------------------------------
template<int NITER>
__global__ __launch_bounds__(256, 2) void flash_kernel(
    const unsigned short* __restrict__ Qg,   // fp16 swizzled [4][32][32][128][8]
    const unsigned short* __restrict__ Kg,   // fp16 [4][4096][256] (k+pos)
    const unsigned short* __restrict__ Vg,   // fp16 [4][256][4096]
    unsigned short* __restrict__ Op,         // fp16 [NS][4][256][4096]
    float* __restrict__ Lm)                  // [NS][4][4096] float2 (m,l)
{
    constexpr int NS  = N_TOK / (NITER * 64);
    constexpr int QSH = (NS == 4) ? 4 : 3;

    __shared__ unsigned short Ks[64 * 256];   // 32KB  K' tile [j][c]
    __shared__ unsigned short Vs[256 * 64];   // 32KB  V tile [c][j]

    const int t    = threadIdx.x;
    const int wave = t >> 6;
    const int lane = t & 63;
    const int l31  = lane & 31;
    const int H    = lane >> 5;    // half: k-split of 32x32x16 operands
    const int lk7  = lane & 7;     // LDS chunk-swizzle key (row&7)

    const int bid = blockIdx.x;
    const int b   = bid & 3;
    const int s   = (bid >> 2) & (NS - 1);
    const int qt  = bid >> QSH;

    const unsigned short* Kb = Kg + (size_t)b * N_TOK * C_DIM;
    const unsigned short* Vb = Vg + (size_t)b * C_DIM * N_TOK;
    // swizzled Q base for this (b, qt): 32 phases x 1024 halves
    const unsigned short* Qw = Qg + (size_t)b * N_TOK * C_DIM + (size_t)qt * 32768;
    const int qoff = (wave * 32 + l31) * 8;

    const int q0 = qt * 128 + wave * 32;

    floatx16 oacc[8];   // O^T[c=cb*32+row(r,H)][q=l31]
#pragma unroll
    for (int cb = 0; cb < 8; cb++)
#pragma unroll
        for (int r = 0; r < 16; r++) oacc[cb][r] = 0.f;
    float m_i = -1e30f;   // running max for q-col (lane-pair consistent)
    float l_i = 0.f;      // per-lane PARTIAL sum (this lane's 32 j's)

    const int jbase = s * (NITER * 64);

    // ---- preamble: stage K tile 0 (LDS[j][cp*8] = global[j][(cp^(j&7))*8])
    {
        const int lr = lane >> 5, cp = lane & 31;
#pragma unroll
        for (int p = 0; p < 8; p++) {
            const int jl = wave * 16 + p * 2 + lr;
            g2l16(Kb + (size_t)(jbase + jl) * C_DIM + (cp ^ (jl & 7)) * 8,
                  &Ks[(wave * 16 + p * 2) * 256]);
        }
    }

    for (int ti = 0; ti < NITER; ti++) {
        const int j0 = jbase + ti * 64;

        __syncthreads();   // B1: K(ti) visible; PV(ti-1) V-reads done

        // ---- stage V(ti) async (flies under S-MFMAs)
        {
            const int lr = lane >> 3, cp = lane & 7;
#pragma unroll
            for (int p = 0; p < 8; p++) {
                const int ob = (p * 4 + wave) * 8;
                const int o  = ob + lr;
                g2l16(Vb + (size_t)o * N_TOK + j0 + (cp ^ (o & 7)) * 8, &Vs[ob * 64]);
            }
        }

        // ---- S^T = K' Q^T (2 j-blocks of 32, K-step c=16)
        // A = K'[j = sb*32+l31][c]; B = Q-frag loaded from swizzled global
        floatx16 sv0, sv1;
        {
            floatx16 a0, a1;
#pragma unroll
            for (int r = 0; r < 16; r++) { a0[r] = 0.f; a1[r] = 0.f; }
            const int rb0 = l31 * 256;
            const int rb1 = (32 + l31) * 256;
            __builtin_amdgcn_s_setprio(1);
#pragma unroll
            for (int ct = 0; ct < 16; ct++) {
                const half8 qv = *(const half8*)&Qw[(ct * 2 + H) * 1024 + qoff];
                const int ch = ((ct * 2 + H) ^ lk7) * 8;
                const half8 k0 = *(const half8*)&Ks[rb0 + ch];
                a0 = __builtin_amdgcn_mfma_f32_32x32x16_f16(k0, qv, a0, 0, 0, 0);
                const half8 k1 = *(const half8*)&Ks[rb1 + ch];
                a1 = __builtin_amdgcn_mfma_f32_32x32x16_f16(k1, qv, a1, 0, 0, 0);
            }
            __builtin_amdgcn_s_setprio(0);
            sv0 = a0; sv1 = a1;
        }

        // ---- per-lane online softmax (32 j's/lane; partner lane^32 has the
        // other 32 of this q-column)
        float mx = sv0[0];
#pragma unroll
        for (int r = 1; r < 16; r++) mx = fmaxf(mx, sv0[r]);
#pragma unroll
        for (int r = 0; r < 16; r++) mx = fmaxf(mx, sv1[r]);
        mx = fmaxf(mx, __shfl_xor(mx, 32));

        // T13 defer-max: skip rescale when tile max growth <= 8
        if (!__all(mx <= m_i + 8.f)) {
            const float mn    = fmaxf(m_i, mx);
            const float alpha = __expf(m_i - mn);
            m_i = mn;
            l_i *= alpha;
#pragma unroll
            for (int cb = 0; cb < 8; cb++)
#pragma unroll
                for (int r = 0; r < 16; r++) oacc[cb][r] *= alpha;
        }
        float ps = 0.f;
#pragma unroll
        for (int r = 0; r < 16; r++) {
            const float p = __expf(sv0[r] - m_i);
            sv0[r] = p; ps += p;
        }
#pragma unroll
        for (int r = 0; r < 16; r++) {
            const float p = __expf(sv1[r] - m_i);
            sv1[r] = p; ps += p;
        }
        l_i += ps;

        // ---- P^T -> PV B-frags (j-pairs packed to half2; lane^32 swap).
        // sv reg r holds row (r&3)+8*(r>>2)+4H of its 32-j block.
        // B-frag word w of pf[jb] = j-pair (jb*16 + H*8 + 2w, +1), col l31.
        half8 pf0, pf1, pf2, pf3;
        {
            const unsigned int p0 = pack2h(sv0[0],  sv0[1]);
            const unsigned int p1 = pack2h(sv0[2],  sv0[3]);
            const unsigned int p2 = pack2h(sv0[4],  sv0[5]);
            const unsigned int p3 = pack2h(sv0[6],  sv0[7]);
            const unsigned int p4 = pack2h(sv0[8],  sv0[9]);
            const unsigned int p5 = pack2h(sv0[10], sv0[11]);
            const unsigned int p6 = pack2h(sv0[12], sv0[13]);
            const unsigned int p7 = pack2h(sv0[14], sv0[15]);
            const unsigned int s0 = __shfl_xor(p0, 32);
            const unsigned int s1 = __shfl_xor(p1, 32);
            const unsigned int s2 = __shfl_xor(p2, 32);
            const unsigned int s3 = __shfl_xor(p3, 32);
            const unsigned int s4 = __shfl_xor(p4, 32);
            const unsigned int s5 = __shfl_xor(p5, 32);
            const unsigned int s6 = __shfl_xor(p6, 32);
            const unsigned int s7 = __shfl_xor(p7, 32);
            union { unsigned int u[4]; half8 h; } a, c;
            a.u[0] = H ? s2 : p0;  a.u[1] = H ? s3 : p1;
            a.u[2] = H ? p2 : s0;  a.u[3] = H ? p3 : s1;
            c.u[0] = H ? s6 : p4;  c.u[1] = H ? s7 : p5;
            c.u[2] = H ? p6 : s4;  c.u[3] = H ? p7 : s5;
            pf0 = a.h; pf1 = c.h;
        }
        {
            const unsigned int p0 = pack2h(sv1[0],  sv1[1]);
            const unsigned int p1 = pack2h(sv1[2],  sv1[3]);
            const unsigned int p2 = pack2h(sv1[4],  sv1[5]);
            const unsigned int p3 = pack2h(sv1[6],  sv1[7]);
            const unsigned int p4 = pack2h(sv1[8],  sv1[9]);
            const unsigned int p5 = pack2h(sv1[10], sv1[11]);
            const unsigned int p6 = pack2h(sv1[12], sv1[13]);
            const unsigned int p7 = pack2h(sv1[14], sv1[15]);
            const unsigned int s0 = __shfl_xor(p0, 32);
            const unsigned int s1 = __shfl_xor(p1, 32);
            const unsigned int s2 = __shfl_xor(p2, 32);
            const unsigned int s3 = __shfl_xor(p3, 32);
            const unsigned int s4 = __shfl_xor(p4, 32);
            const unsigned int s5 = __shfl_xor(p5, 32);
            const unsigned int s6 = __shfl_xor(p6, 32);
            const unsigned int s7 = __shfl_xor(p7, 32);
            union { unsigned int u[4]; half8 h; } a, c;
            a.u[0] = H ? s2 : p0;  a.u[1] = H ? s3 : p1;
            a.u[2] = H ? p2 : s0;  a.u[3] = H ? p3 : s1;
            c.u[0] = H ? s6 : p4;  c.u[1] = H ? s7 : p5;
            c.u[2] = H ? p6 : s4;  c.u[3] = H ? p7 : s5;
            pf2 = a.h; pf3 = c.h;
        }

        __syncthreads();   // B2: V(ti) visible; all waves done reading K(ti)

        // ---- stage K(ti+1) async (flies under PV-MFMAs)
        if (ti < NITER - 1) {
            const int lr = lane >> 5, cp = lane & 31;
#pragma unroll
            for (int p = 0; p < 8; p++) {
                const int jl = wave * 16 + p * 2 + lr;
                g2l16(Kb + (size_t)(j0 + 64 + jl) * C_DIM + (cp ^ (jl & 7)) * 8,
                      &Ks[(wave * 16 + p * 2) * 256]);
            }
        }

        // ---- O^T += V P^T  (A = V[c=cb*32+l31][j-chunk jb*16+H*8])
        __builtin_amdgcn_s_setprio(1);
#pragma unroll
        for (int cb = 0; cb < 8; cb++) {
            const int vb = (cb * 32 + l31) * 64;
            const half8 av0 = *(const half8*)&Vs[vb + (((0 + H) ^ lk7) * 8)];
            oacc[cb] = __builtin_amdgcn_mfma_f32_32x32x16_f16(av0, pf0, oacc[cb], 0, 0, 0);
            const half8 av1 = *(const half8*)&Vs[vb + (((2 + H) ^ lk7) * 8)];
            oacc[cb] = __builtin_amdgcn_mfma_f32_32x32x16_f16(av1, pf1, oacc[cb], 0, 0, 0);
            const half8 av2 = *(const half8*)&Vs[vb + (((4 + H) ^ lk7) * 8)];
            oacc[cb] = __builtin_amdgcn_mfma_f32_32x32x16_f16(av2, pf2, oacc[cb], 0, 0, 0);
            const half8 av3 = *(const half8*)&Vs[vb + (((6 + H) ^ lk7) * 8)];
            oacc[cb] = __builtin_amdgcn_mfma_f32_32x32x16_f16(av3, pf3, oacc[cb], 0, 0, 0);
        }
        __builtin_amdgcn_s_setprio(0);
    }

    // ---- epilogue: unnormalized O^T fp16 + (m,l)
    unsigned short* Ob = Op + ((size_t)(s * 4 + b) * C_DIM) * N_TOK;
    const int n = q0 + l31;
#pragma unroll
    for (int cb = 0; cb < 8; cb++) {
#pragma unroll
        for (int r = 0; r < 16; r++) {
            const int c = cb * 32 + (r & 3) + 8 * (r >> 2) + 4 * H;
            Ob[(size_t)c * N_TOK + n] = f2h(oacc[cb][r]);
        }
    }
    float lt = l_i + __shfl_xor(l_i, 32);
    if (H == 0) {
        const size_t nb = (size_t)(s * 4 + b) * N_TOK + n;
        *(float2*)&Lm[nb * 2] = make_float2(m_i, lt);
    }
}

// ---------------------------------------------------------------------------
// merge_kernel: out = gamma * (sum_s w_s O_s) / (sum_s w_s l_s) + x
// ---------------------------------------------------------------------------
template<int NS>
__global__ __launch_bounds__(256) void merge_kernel(
    const unsigned short* __restrict__ Op,
    const float* __restrict__ Lm,
    const float* __restrict__ x,
    const float* __restrict__ gamma,
    float* __restrict__ out)
{
    const int blk = blockIdx.x;          // 4096
    const int b   = blk >> 10;
    const int c   = (blk >> 2) & 255;
    const int nq  = blk & 3;
    const int n0  = nq * 1024 + threadIdx.x * 4;

    const size_t NEo = (size_t)4 * C_DIM * N_TOK;
    const size_t obase = ((size_t)b * C_DIM + c) * N_TOK + n0;

    float ms[NS][4], ls[NS][4], os[NS][4];
#pragma unroll
    for (int s = 0; s < NS; s++) {
        const uint2 u = *(const uint2*)&Op[s * NEo + obase];
        os[s][0] = h2f((unsigned short)(u.x & 0xffff));
        os[s][1] = h2f((unsigned short)(u.x >> 16));
        os[s][2] = h2f((unsigned short)(u.y & 0xffff));
        os[s][3] = h2f((unsigned short)(u.y >> 16));
        const float* Lms = Lm + (size_t)(s * 4 + b) * N_TOK * 2;
        const float4 A0 = *(const float4*)&Lms[n0 * 2];
        const float4 A1 = *(const float4*)&Lms[n0 * 2 + 4];
        ms[s][0] = A0.x; ls[s][0] = A0.y;
        ms[s][1] = A0.z; ls[s][1] = A0.w;
        ms[s][2] = A1.x; ls[s][2] = A1.y;
        ms[s][3] = A1.z; ls[s][3] = A1.w;
    }
    const float4 xv = *(const float4*)&x[obase];
    const float xin[4] = {xv.x, xv.y, xv.z, xv.w};
    const float g = gamma[0];

    float4 res;
    float* rp = (float*)&res;
#pragma unroll
    for (int i = 0; i < 4; i++) {
        float M = ms[0][i];
#pragma unroll
        for (int s = 1; s < NS; s++) M = fmaxf(M, ms[s][i]);
        float osum = 0.f, lsum = 0.f;
#pragma unroll
        for (int s = 0; s < NS; s++) {
            const float w = __expf(ms[s][i] - M);
            osum += w * os[s][i];
            lsum += w * ls[s][i];
        }
        rp[i] = g * osum / lsum + xin[i];
    }
    *(float4*)&out[obase] = res;
}

extern "C" void kernel_launch(void* const* d_in, const int* in_sizes, int n_in,
                              void* d_out, int out_size, void* d_ws, size_t ws_size,
                              hipStream_t stream) {
    const float* x     = (const float*)d_in[0];
    const float* Wq    = (const float*)d_in[1];
    const float* bq    = (const float*)d_in[2];
    const float* Wk    = (const float*)d_in[3];
    const float* bk    = (const float*)d_in[4];
    const float* Wv    = (const float*)d_in[5];
    const float* bv    = (const float*)d_in[6];
    const float* relh  = (const float*)d_in[7];
    const float* relw  = (const float*)d_in[8];
    const float* gamma = (const float*)d_in[9];
    float* out = (float*)d_out;

    const size_t NE = (size_t)4 * N_TOK * C_DIM;   // 4.19M elems

    // NS=4 needs: Op 4NE u16 + W 6*65536 u16 + QKV 3NE u16 + Lm 4*4*4096*2 f32
    const size_t need4 = ((size_t)7 * NE + 6 * 65536) * 2 + (size_t)4 * 4 * N_TOK * 2 * 4;
    const int NS = (ws_size >= need4) ? 4 : 2;

    // Region layout (Op overlays Xhi/Xlo: X dead before flash writes Op)
    unsigned short* Op  = (unsigned short*)d_ws;           // NS*NE u16
    unsigned short* Xhi = Op;                              // NE u16 (prep/proj only)
    unsigned short* Xlo = Op + NE;                         // NE u16
    unsigned short* Whi = Op + (size_t)NS * NE;            // 3*65536 u16
    unsigned short* Wlo = Whi + 3 * 65536;
    unsigned short* Qh  = Wlo + 3 * 65536;                 // NE u16 (fp16, swizzled)
    unsigned short* Kh  = Qh + NE;                         // NE u16 (fp16)
    unsigned short* Vh  = Kh + NE;                         // NE u16 (fp16)
    float* Lm = (float*)(Vh + NE);                         // NS*4*4096*2 floats

    hipLaunchKernelGGL(prep_kernel, dim3(1027), dim3(256), 0, stream,
                       x, Wq, Wk, Wv, Xhi, Xlo, Whi, Wlo);
    hipLaunchKernelGGL(proj_kernel, dim3(768), dim3(256), 0, stream,
                       Xhi, Xlo, Whi, Wlo, bq, bk, bv, relh, relw, Qh, Kh, Vh);
    if (NS == 4) {
        hipLaunchKernelGGL((flash_kernel<16>), dim3(512), dim3(256), 0, stream,
                           Qh, Kh, Vh, Op, Lm);
        hipLaunchKernelGGL((merge_kernel<4>), dim3(4096), dim3(256), 0, stream,
                           Op, Lm, x, gamma, out);
    } else {
        hipLaunchKernelGGL((flash_kernel<32>), dim3(256), dim3(256), 0, stream,
                           Qh, Kh, Vh, Op, Lm);
        hipLaunchKernelGGL((merge_kernel<2>), dim3(4096), dim3(256), 0, stream,
                           Op, Lm, x, gamma, out);
    }
}

// Round 6
// 320.946 us; speedup vs baseline: 1.4483x; 1.4483x over previous
//
#include <hip/hip_runtime.h>
#include <stdint.h>

#define N_TOK 4096
#define C_DIM 256

typedef __attribute__((ext_vector_type(8))) short short8;
typedef __attribute__((ext_vector_type(8))) _Float16 half8;
typedef __attribute__((ext_vector_type(4))) float floatx4;
typedef __attribute__((ext_vector_type(16))) float floatx16;
typedef __attribute__((ext_vector_type(4))) unsigned short ushort4v;

__device__ __forceinline__ unsigned short bf16_rne(float f) {
    union { float f; unsigned int u; } v; v.f = f;
    unsigned int u = v.u;
    unsigned int rounded = u + 0x7FFFu + ((u >> 16) & 1u);
    return (unsigned short)(rounded >> 16);
}
__device__ __forceinline__ float bf16_to_f(unsigned short h) {
    union { unsigned int u; float f; } v; v.u = ((unsigned int)h) << 16;
    return v.f;
}
__device__ __forceinline__ void split_bf16(float f, unsigned short& h, unsigned short& l) {
    h = bf16_rne(f);
    l = bf16_rne(f - bf16_to_f(h));
}
__device__ __forceinline__ unsigned short f2h(float f) {
    union { _Float16 h; unsigned short u; } v; v.h = (_Float16)f; return v.u;
}
__device__ __forceinline__ float h2f(unsigned short u) {
    union { unsigned short u; _Float16 h; } v; v.u = u; return (float)v.h;
}
// pack two floats -> half2 (RNE)
__device__ __forceinline__ unsigned int pack2h(float a, float b) {
    union { _Float16 h[2]; unsigned int u; } v;
    v.h[0] = (_Float16)a; v.h[1] = (_Float16)b;
    return v.u;
}
// async global->LDS 16B/lane; LDS dest = wave-uniform base + lane*16
__device__ __forceinline__ void g2l16(const void* g, void* l) {
    __builtin_amdgcn_global_load_lds(
        (const __attribute__((address_space(1))) void*)g,
        (__attribute__((address_space(3))) void*)l, 16, 0, 0);
}

// ---------------------------------------------------------------------------
// prep_kernel: one-time split/transpose (bf16 hi/lo pairs for fp32-accurate
// projection GEMM).  (unchanged)
// ---------------------------------------------------------------------------
__global__ __launch_bounds__(256) void prep_kernel(
    const float* __restrict__ x,
    const float* __restrict__ Wq, const float* __restrict__ Wk, const float* __restrict__ Wv,
    unsigned short* __restrict__ Xhi, unsigned short* __restrict__ Xlo,
    unsigned short* __restrict__ Whi, unsigned short* __restrict__ Wlo)
{
    const int t = threadIdx.x;
    if (blockIdx.x >= 1024) {
        const int pj = blockIdx.x - 1024;
        const float* W = (pj == 0) ? Wq : (pj == 1) ? Wk : Wv;
        unsigned short* dh = Whi + pj * 65536;
        unsigned short* dl = Wlo + pj * 65536;
        for (int it = 0; it < 64; it++) {
            const int idx = it * 1024 + t * 4;
            const float4 w = *(const float4*)&W[idx];
            unsigned short h0, l0, h1, l1, h2, l2, h3, l3;
            split_bf16(w.x, h0, l0); split_bf16(w.y, h1, l1);
            split_bf16(w.z, h2, l2); split_bf16(w.w, h3, l3);
            ushort4v vh; vh[0] = h0; vh[1] = h1; vh[2] = h2; vh[3] = h3;
            ushort4v vl; vl[0] = l0; vl[1] = l1; vl[2] = l2; vl[3] = l3;
            *(ushort4v*)&dh[idx] = vh;
            *(ushort4v*)&dl[idx] = vl;
        }
        return;
    }
    __shared__ float Xs[64 * 65];   // pitch 65: conflict-free transpose
    const int b  = blockIdx.x >> 8;
    const int ct = (blockIdx.x >> 6) & 3;
    const int nt = blockIdx.x & 63;
    const int c0 = ct * 64, n0 = nt * 64;
    {
        const int nch = t & 15, cr = t >> 4;
#pragma unroll
        for (int pass = 0; pass < 4; pass++) {
            const int c = pass * 16 + cr;
            const float4 v = *(const float4*)&x[((size_t)(b * C_DIM + c0 + c)) * N_TOK + n0 + nch * 4];
            float* row = &Xs[c * 65 + nch * 4];
            row[0] = v.x; row[1] = v.y; row[2] = v.z; row[3] = v.w;
        }
    }
    __syncthreads();
    {
        const int n = t >> 2, cc = t & 3;
        short8 vh0, vl0, vh1, vl1;
#pragma unroll
        for (int i = 0; i < 8; i++) {
            unsigned short h, l;
            split_bf16(Xs[(cc * 16 + i) * 65 + n], h, l);
            vh0[i] = (short)h; vl0[i] = (short)l;
        }
#pragma unroll
        for (int i = 0; i < 8; i++) {
            unsigned short h, l;
            split_bf16(Xs[(cc * 16 + 8 + i) * 65 + n], h, l);
            vh1[i] = (short)h; vl1[i] = (short)l;
        }
        const size_t off = ((size_t)b * N_TOK + n0 + n) * C_DIM + c0 + cc * 16;
        *(short8*)&Xhi[off] = vh0; *(short8*)&Xhi[off + 8] = vh1;
        *(short8*)&Xlo[off] = vl0; *(short8*)&Xlo[off + 8] = vl1;
    }
}

// ---------------------------------------------------------------------------
// proj_kernel: Out[n,o] = sum_c x[n,c]*W[o,c] + bias (+pos for K').
// Q output SWIZZLED for the 32x32 flash B-frag loads:
//   Qh[b][qt=n>>7][phase=(o>>3)][q=n&127][i=o&7]
// ---------------------------------------------------------------------------
__global__ __launch_bounds__(256) void proj_kernel(
    const unsigned short* __restrict__ Xhi, const unsigned short* __restrict__ Xlo,
    const unsigned short* __restrict__ Whi, const unsigned short* __restrict__ Wlo,
    const float* __restrict__ bq, const float* __restrict__ bk, const float* __restrict__ bv,
    const float* __restrict__ relh, const float* __restrict__ relw,
    unsigned short* __restrict__ Qh,
    unsigned short* __restrict__ Kh,
    unsigned short* __restrict__ Vh)
{
    __shared__ unsigned short SM[20480];   // 40KB carve
    unsigned short* Ah = SM;               // [64][32]
    unsigned short* Al = SM + 2048;
    unsigned short* Bh = SM + 4096;        // [256][32]
    unsigned short* Bl = SM + 12288;

    const int t    = threadIdx.x;
    const int wave = t >> 6;
    const int lane = t & 63;
    const int l15  = lane & 15;
    const int quad = lane >> 4;

    const int bp   = blockIdx.x >> 6;
    const int proj = bp % 3;
    const int b    = bp / 3;
    const int n0   = (blockIdx.x & 63) * 64;

    const unsigned short* Xh = Xhi + ((size_t)b * N_TOK + n0) * C_DIM;
    const unsigned short* Xl = Xlo + ((size_t)b * N_TOK + n0) * C_DIM;
    const unsigned short* Wh = Whi + proj * 65536;
    const unsigned short* Wl = Wlo + proj * 65536;
    const float* bias = (proj == 0) ? bq : (proj == 1) ? bk : bv;
    const bool needlo = (proj < 2);

    floatx4 acc[16];
#pragma unroll
    for (int i = 0; i < 16; i++) acc[i] = (floatx4){0.f, 0.f, 0.f, 0.f};

    for (int c0 = 0; c0 < 256; c0 += 32) {
        {
            const int lr = lane >> 2, cp = lane & 3;
            const int key = (lr ^ (lr >> 2)) & 3;
            const int r = wave * 16 + lr;
            g2l16(Xh + (size_t)r * C_DIM + c0 + (cp ^ key) * 8, &Ah[wave * 512]);
            if (needlo) g2l16(Xl + (size_t)r * C_DIM + c0 + (cp ^ key) * 8, &Al[wave * 512]);
#pragma unroll
            for (int p = 0; p < 4; p++) {
                const int rb = (p * 4 + wave) * 16;
                const int rr = rb + lr;
                g2l16(Wh + (size_t)rr * 256 + c0 + (cp ^ key) * 8, &Bh[rb * 32]);
                if (needlo) g2l16(Wl + (size_t)rr * 256 + c0 + (cp ^ key) * 8, &Bl[rb * 32]);
            }
        }
        __syncthreads();

        const int akey = (l15 ^ (l15 >> 2)) & 3;
        const int arow = (wave * 16 + l15) * 32 + ((quad ^ akey) * 8);
        const short8 a_h = *(const short8*)&Ah[arow];
        short8 a_l;
        if (needlo) a_l = *(const short8*)&Al[arow];
#pragma unroll
        for (int ot = 0; ot < 16; ot++) {
            const int brow = (ot * 16 + l15) * 32 + ((quad ^ akey) * 8);
            const short8 b_h = *(const short8*)&Bh[brow];
            acc[ot] = __builtin_amdgcn_mfma_f32_16x16x32_bf16(a_h, b_h, acc[ot], 0, 0, 0);
            if (needlo) {
                const short8 b_l = *(const short8*)&Bl[brow];
                acc[ot] = __builtin_amdgcn_mfma_f32_16x16x32_bf16(a_l, b_h, acc[ot], 0, 0, 0);
                acc[ot] = __builtin_amdgcn_mfma_f32_16x16x32_bf16(a_h, b_l, acc[ot], 0, 0, 0);
            }
        }
        __syncthreads();
    }

    // ---- epilogue (all fp16 outputs) ----
    const int h0 = n0 >> 6;   // pos[c][n] = relh[c][n>>6] + relw[c][n&63]
    if (proj == 0) {
        // swizzled Q: [qt][phase=o>>3][q128][i=o&7]
        unsigned short* Og = Qh + (size_t)b * N_TOK * C_DIM;
#pragma unroll
        for (int ot = 0; ot < 16; ot++) {
            const int o = ot * 16 + l15;
            const float bs = bias[o];
            const int phase = o >> 3;       // = ot*2 + (l15>>3)
            const int ii    = o & 7;
#pragma unroll
            for (int r = 0; r < 4; r++) {
                const int n  = n0 + wave * 16 + quad * 4 + r;
                const int qt = n >> 7, q128 = n & 127;
                Og[(size_t)qt * 32768 + phase * 1024 + q128 * 8 + ii] = f2h(acc[ot][r] + bs);
            }
        }
    } else if (proj == 1) {
        unsigned short* Og = Kh + ((size_t)b * N_TOK + n0) * C_DIM;
#pragma unroll
        for (int ot = 0; ot < 16; ot++) {
            const int o = ot * 16 + l15;
            const float bs = bias[o];
            const float ph = relh[o * 64 + h0];
#pragma unroll
            for (int r = 0; r < 4; r++) {
                const int nl = wave * 16 + quad * 4 + r;
                Og[(size_t)nl * C_DIM + o] = f2h(acc[ot][r] + bs + ph + relw[o * 64 + nl]);
            }
        }
    } else {
        // V: fp16, transpose via LDS (reuse SM: 256x72 shorts = 36KB)
        unsigned short* Vt = SM;
#pragma unroll
        for (int ot = 0; ot < 16; ot++) {
            const int o = ot * 16 + l15;
            const float bs = bias[o];
            const unsigned int u0 = (unsigned int)f2h(acc[ot][0] + bs) |
                                    ((unsigned int)f2h(acc[ot][1] + bs) << 16);
            const unsigned int u1 = (unsigned int)f2h(acc[ot][2] + bs) |
                                    ((unsigned int)f2h(acc[ot][3] + bs) << 16);
            uint2 uv; uv.x = u0; uv.y = u1;
            *(uint2*)&Vt[o * 72 + wave * 16 + quad * 4] = uv;
        }
        __syncthreads();
        const int ch   = t & 7;
        const int orow = t >> 3;
#pragma unroll
        for (int pass = 0; pass < 8; pass++) {
            const int o = pass * 32 + orow;
            const short8 vv = *(const short8*)&Vt[o * 72 + ch * 8];
            *(short8*)&Vh[((size_t)b * C_DIM + o) * N_TOK + n0 + ch * 8] = vv;
        }
    }
}

// ---------------------------------------------------------------------------
// flash_kernel v8: identical numerics to v6/v7 (both PASSED, absmax
// 0.0390625); the ONLY change vs v7 is the launch-bounds cap.
// Empirical cap model on this toolchain (unified VGPR+AGPR file):
//   (512,4) -> 64 regs [r1], (256,2) -> 128 regs [r2,r4,r5]  =>  cap = 256/arg2.
// The 32x32 kernel needs ~220 unified regs (oacc 128 AGPR + ~90 arch), so
// the 128 cap of (256,2) forced ~1.2GB/dispatch scratch spill regardless of
// source-level shaving (r5 proved: removing 64 resident regs changed spill
// by 0 bytes).  (256,1) -> cap 256: fits, and 129-256 regs/wave still gives
// the 8-waves/CU tier (two 256-thread blocks/CU) per the occupancy steps.
// ---------------------------------------------------------------------------
template<int NITER>
__global__ __launch_bounds__(256, 1) void flash_kernel(
    const unsigned short* __restrict__ Qg,   // fp16 swizzled [4][32][32][128][8]
    const unsigned short* __restrict__ Kg,   // fp16 [4][4096][256] (k+pos)
    const unsigned short* __restrict__ Vg,   // fp16 [4][256][4096]
    unsigned short* __restrict__ Op,         // fp16 [NS][4][256][4096]
    float* __restrict__ Lm)                  // [NS][4][4096] float2 (m,l)
{
    constexpr int NS  = N_TOK / (NITER * 64);
    constexpr int QSH = (NS == 4) ? 4 : 3;

    __shared__ unsigned short Ks[64 * 256];   // 32KB  K' tile [j][c]
    __shared__ unsigned short Vs[256 * 64];   // 32KB  V tile [c][j]

    const int t    = threadIdx.x;
    const int wave = t >> 6;
    const int lane = t & 63;
    const int l31  = lane & 31;
    const int H    = lane >> 5;    // half: k-split of 32x32x16 operands
    const int lk7  = lane & 7;     // LDS chunk-swizzle key (row&7)

    const int bid = blockIdx.x;
    const int b   = bid & 3;
    const int s   = (bid >> 2) & (NS - 1);
    const int qt  = bid >> QSH;

    const unsigned short* Kb = Kg + (size_t)b * N_TOK * C_DIM;
    const unsigned short* Vb = Vg + (size_t)b * C_DIM * N_TOK;
    // swizzled Q base for this (b, qt): 32 phases x 1024 halves
    const unsigned short* Qw = Qg + (size_t)b * N_TOK * C_DIM + (size_t)qt * 32768;
    const int qoff = (wave * 32 + l31) * 8;

    const int q0 = qt * 128 + wave * 32;

    floatx16 oacc[8];   // O^T[c=cb*32+row(r,H)][q=l31]
#pragma unroll
    for (int cb = 0; cb < 8; cb++)
#pragma unroll
        for (int r = 0; r < 16; r++) oacc[cb][r] = 0.f;
    float m_i = -1e30f;   // running max for q-col (lane-pair consistent)
    float l_i = 0.f;      // per-lane PARTIAL sum (this lane's 32 j's)

    const int jbase = s * (NITER * 64);

    // ---- preamble: stage K tile 0 (LDS[j][cp*8] = global[j][(cp^(j&7))*8])
    {
        const int lr = lane >> 5, cp = lane & 31;
#pragma unroll
        for (int p = 0; p < 8; p++) {
            const int jl = wave * 16 + p * 2 + lr;
            g2l16(Kb + (size_t)(jbase + jl) * C_DIM + (cp ^ (jl & 7)) * 8,
                  &Ks[(wave * 16 + p * 2) * 256]);
        }
    }

    for (int ti = 0; ti < NITER; ti++) {
        const int j0 = jbase + ti * 64;

        __syncthreads();   // B1: K(ti) visible; PV(ti-1) V-reads done

        // ---- stage V(ti) async (flies under S-MFMAs)
        {
            const int lr = lane >> 3, cp = lane & 7;
#pragma unroll
            for (int p = 0; p < 8; p++) {
                const int ob = (p * 4 + wave) * 8;
                const int o  = ob + lr;
                g2l16(Vb + (size_t)o * N_TOK + j0 + (cp ^ (o & 7)) * 8, &Vs[ob * 64]);
            }
        }

        // ---- S^T = K' Q^T (2 j-blocks of 32, K-step c=16)
        // A = K'[j = sb*32+l31][c]; B = Q-frag loaded from swizzled global
        floatx16 sv0, sv1;
        {
            floatx16 a0, a1;
#pragma unroll
            for (int r = 0; r < 16; r++) { a0[r] = 0.f; a1[r] = 0.f; }
            const int rb0 = l31 * 256;
            const int rb1 = (32 + l31) * 256;
            __builtin_amdgcn_s_setprio(1);
#pragma unroll
            for (int ct = 0; ct < 16; ct++) {
                const half8 qv = *(const half8*)&Qw[(ct * 2 + H) * 1024 + qoff];
                const int ch = ((ct * 2 + H) ^ lk7) * 8;
                const half8 k0 = *(const half8*)&Ks[rb0 + ch];
                a0 = __builtin_amdgcn_mfma_f32_32x32x16_f16(k0, qv, a0, 0, 0, 0);
                const half8 k1 = *(const half8*)&Ks[rb1 + ch];
                a1 = __builtin_amdgcn_mfma_f32_32x32x16_f16(k1, qv, a1, 0, 0, 0);
            }
            __builtin_amdgcn_s_setprio(0);
            sv0 = a0; sv1 = a1;
        }

        // ---- per-lane online softmax (32 j's/lane; partner lane^32 has the
        // other 32 of this q-column)
        float mx = sv0[0];
#pragma unroll
        for (int r = 1; r < 16; r++) mx = fmaxf(mx, sv0[r]);
#pragma unroll
        for (int r = 0; r < 16; r++) mx = fmaxf(mx, sv1[r]);
        mx = fmaxf(mx, __shfl_xor(mx, 32));

        // T13 defer-max: skip rescale when tile max growth <= 8
        if (!__all(mx <= m_i + 8.f)) {
            const float mn    = fmaxf(m_i, mx);
            const float alpha = __expf(m_i - mn);
            m_i = mn;
            l_i *= alpha;
#pragma unroll
            for (int cb = 0; cb < 8; cb++)
#pragma unroll
                for (int r = 0; r < 16; r++) oacc[cb][r] *= alpha;
        }
        float ps = 0.f;
#pragma unroll
        for (int r = 0; r < 16; r++) {
            const float p = __expf(sv0[r] - m_i);
            sv0[r] = p; ps += p;
        }
#pragma unroll
        for (int r = 0; r < 16; r++) {
            const float p = __expf(sv1[r] - m_i);
            sv1[r] = p; ps += p;
        }
        l_i += ps;

        // ---- P^T -> PV B-frags (j-pairs packed to half2; lane^32 swap).
        // sv reg r holds row (r&3)+8*(r>>2)+4H of its 32-j block.
        // B-frag word w of pf[jb] = j-pair (jb*16 + H*8 + 2w, +1), col l31.
        half8 pf0, pf1, pf2, pf3;
        {
            const unsigned int p0 = pack2h(sv0[0],  sv0[1]);
            const unsigned int p1 = pack2h(sv0[2],  sv0[3]);
            const unsigned int p2 = pack2h(sv0[4],  sv0[5]);
            const unsigned int p3 = pack2h(sv0[6],  sv0[7]);
            const unsigned int p4 = pack2h(sv0[8],  sv0[9]);
            const unsigned int p5 = pack2h(sv0[10], sv0[11]);
            const unsigned int p6 = pack2h(sv0[12], sv0[13]);
            const unsigned int p7 = pack2h(sv0[14], sv0[15]);
            const unsigned int s0 = __shfl_xor(p0, 32);
            const unsigned int s1 = __shfl_xor(p1, 32);
            const unsigned int s2 = __shfl_xor(p2, 32);
            const unsigned int s3 = __shfl_xor(p3, 32);
            const unsigned int s4 = __shfl_xor(p4, 32);
            const unsigned int s5 = __shfl_xor(p5, 32);
            const unsigned int s6 = __shfl_xor(p6, 32);
            const unsigned int s7 = __shfl_xor(p7, 32);
            union { unsigned int u[4]; half8 h; } a, c;
            a.u[0] = H ? s2 : p0;  a.u[1] = H ? s3 : p1;
            a.u[2] = H ? p2 : s0;  a.u[3] = H ? p3 : s1;
            c.u[0] = H ? s6 : p4;  c.u[1] = H ? s7 : p5;
            c.u[2] = H ? p6 : s4;  c.u[3] = H ? p7 : s5;
            pf0 = a.h; pf1 = c.h;
        }
        {
            const unsigned int p0 = pack2h(sv1[0],  sv1[1]);
            const unsigned int p1 = pack2h(sv1[2],  sv1[3]);
            const unsigned int p2 = pack2h(sv1[4],  sv1[5]);
            const unsigned int p3 = pack2h(sv1[6],  sv1[7]);
            const unsigned int p4 = pack2h(sv1[8],  sv1[9]);
            const unsigned int p5 = pack2h(sv1[10], sv1[11]);
            const unsigned int p6 = pack2h(sv1[12], sv1[13]);
            const unsigned int p7 = pack2h(sv1[14], sv1[15]);
            const unsigned int s0 = __shfl_xor(p0, 32);
            const unsigned int s1 = __shfl_xor(p1, 32);
            const unsigned int s2 = __shfl_xor(p2, 32);
            const unsigned int s3 = __shfl_xor(p3, 32);
            const unsigned int s4 = __shfl_xor(p4, 32);
            const unsigned int s5 = __shfl_xor(p5, 32);
            const unsigned int s6 = __shfl_xor(p6, 32);
            const unsigned int s7 = __shfl_xor(p7, 32);
            union { unsigned int u[4]; half8 h; } a, c;
            a.u[0] = H ? s2 : p0;  a.u[1] = H ? s3 : p1;
            a.u[2] = H ? p2 : s0;  a.u[3] = H ? p3 : s1;
            c.u[0] = H ? s6 : p4;  c.u[1] = H ? s7 : p5;
            c.u[2] = H ? p6 : s4;  c.u[3] = H ? p7 : s5;
            pf2 = a.h; pf3 = c.h;
        }

        __syncthreads();   // B2: V(ti) visible; all waves done reading K(ti)

        // ---- stage K(ti+1) async (flies under PV-MFMAs)
        if (ti < NITER - 1) {
            const int lr = lane >> 5, cp = lane & 31;
#pragma unroll
            for (int p = 0; p < 8; p++) {
                const int jl = wave * 16 + p * 2 + lr;
                g2l16(Kb + (size_t)(j0 + 64 + jl) * C_DIM + (cp ^ (jl & 7)) * 8,
                      &Ks[(wave * 16 + p * 2) * 256]);
            }
        }

        // ---- O^T += V P^T  (A = V[c=cb*32+l31][j-chunk jb*16+H*8])
        __builtin_amdgcn_s_setprio(1);
#pragma unroll
        for (int cb = 0; cb < 8; cb++) {
            const int vb = (cb * 32 + l31) * 64;
            const half8 av0 = *(const half8*)&Vs[vb + (((0 + H) ^ lk7) * 8)];
            oacc[cb] = __builtin_amdgcn_mfma_f32_32x32x16_f16(av0, pf0, oacc[cb], 0, 0, 0);
            const half8 av1 = *(const half8*)&Vs[vb + (((2 + H) ^ lk7) * 8)];
            oacc[cb] = __builtin_amdgcn_mfma_f32_32x32x16_f16(av1, pf1, oacc[cb], 0, 0, 0);
            const half8 av2 = *(const half8*)&Vs[vb + (((4 + H) ^ lk7) * 8)];
            oacc[cb] = __builtin_amdgcn_mfma_f32_32x32x16_f16(av2, pf2, oacc[cb], 0, 0, 0);
            const half8 av3 = *(const half8*)&Vs[vb + (((6 + H) ^ lk7) * 8)];
            oacc[cb] = __builtin_amdgcn_mfma_f32_32x32x16_f16(av3, pf3, oacc[cb], 0, 0, 0);
        }
        __builtin_amdgcn_s_setprio(0);
    }

    // ---- epilogue: unnormalized O^T fp16 + (m,l)
    unsigned short* Ob = Op + ((size_t)(s * 4 + b) * C_DIM) * N_TOK;
    const int n = q0 + l31;
#pragma unroll
    for (int cb = 0; cb < 8; cb++) {
#pragma unroll
        for (int r = 0; r < 16; r++) {
            const int c = cb * 32 + (r & 3) + 8 * (r >> 2) + 4 * H;
            Ob[(size_t)c * N_TOK + n] = f2h(oacc[cb][r]);
        }
    }
    float lt = l_i + __shfl_xor(l_i, 32);
    if (H == 0) {
        const size_t nb = (size_t)(s * 4 + b) * N_TOK + n;
        *(float2*)&Lm[nb * 2] = make_float2(m_i, lt);
    }
}

// ---------------------------------------------------------------------------
// merge_kernel: out = gamma * (sum_s w_s O_s) / (sum_s w_s l_s) + x
// ---------------------------------------------------------------------------
template<int NS>
__global__ __launch_bounds__(256) void merge_kernel(
    const unsigned short* __restrict__ Op,
    const float* __restrict__ Lm,
    const float* __restrict__ x,
    const float* __restrict__ gamma,
    float* __restrict__ out)
{
    const int blk = blockIdx.x;          // 4096
    const int b   = blk >> 10;
    const int c   = (blk >> 2) & 255;
    const int nq  = blk & 3;
    const int n0  = nq * 1024 + threadIdx.x * 4;

    const size_t NEo = (size_t)4 * C_DIM * N_TOK;
    const size_t obase = ((size_t)b * C_DIM + c) * N_TOK + n0;

    float ms[NS][4], ls[NS][4], os[NS][4];
#pragma unroll
    for (int s = 0; s < NS; s++) {
        const uint2 u = *(const uint2*)&Op[s * NEo + obase];
        os[s][0] = h2f((unsigned short)(u.x & 0xffff));
        os[s][1] = h2f((unsigned short)(u.x >> 16));
        os[s][2] = h2f((unsigned short)(u.y & 0xffff));
        os[s][3] = h2f((unsigned short)(u.y >> 16));
        const float* Lms = Lm + (size_t)(s * 4 + b) * N_TOK * 2;
        const float4 A0 = *(const float4*)&Lms[n0 * 2];
        const float4 A1 = *(const float4*)&Lms[n0 * 2 + 4];
        ms[s][0] = A0.x; ls[s][0] = A0.y;
        ms[s][1] = A0.z; ls[s][1] = A0.w;
        ms[s][2] = A1.x; ls[s][2] = A1.y;
        ms[s][3] = A1.z; ls[s][3] = A1.w;
    }
    const float4 xv = *(const float4*)&x[obase];
    const float xin[4] = {xv.x, xv.y, xv.z, xv.w};
    const float g = gamma[0];

    float4 res;
    float* rp = (float*)&res;
#pragma unroll
    for (int i = 0; i < 4; i++) {
        float M = ms[0][i];
#pragma unroll
        for (int s = 1; s < NS; s++) M = fmaxf(M, ms[s][i]);
        float osum = 0.f, lsum = 0.f;
#pragma unroll
        for (int s = 0; s < NS; s++) {
            const float w = __expf(ms[s][i] - M);
            osum += w * os[s][i];
            lsum += w * ls[s][i];
        }
        rp[i] = g * osum / lsum + xin[i];
    }
    *(float4*)&out[obase] = res;
}

extern "C" void kernel_launch(void* const* d_in, const int* in_sizes, int n_in,
                              void* d_out, int out_size, void* d_ws, size_t ws_size,
                              hipStream_t stream) {
    const float* x     = (const float*)d_in[0];
    const float* Wq    = (const float*)d_in[1];
    const float* bq    = (const float*)d_in[2];
    const float* Wk    = (const float*)d_in[3];
    const float* bk    = (const float*)d_in[4];
    const float* Wv    = (const float*)d_in[5];
    const float* bv    = (const float*)d_in[6];
    const float* relh  = (const float*)d_in[7];
    const float* relw  = (const float*)d_in[8];
    const float* gamma = (const float*)d_in[9];
    float* out = (float*)d_out;

    const size_t NE = (size_t)4 * N_TOK * C_DIM;   // 4.19M elems

    // NS=4 needs: Op 4NE u16 + W 6*65536 u16 + QKV 3NE u16 + Lm 4*4*4096*2 f32
    const size_t need4 = ((size_t)7 * NE + 6 * 65536) * 2 + (size_t)4 * 4 * N_TOK * 2 * 4;
    const int NS = (ws_size >= need4) ? 4 : 2;

    // Region layout (Op overlays Xhi/Xlo: X dead before flash writes Op)
    unsigned short* Op  = (unsigned short*)d_ws;           // NS*NE u16
    unsigned short* Xhi = Op;                              // NE u16 (prep/proj only)
    unsigned short* Xlo = Op + NE;                         // NE u16
    unsigned short* Whi = Op + (size_t)NS * NE;            // 3*65536 u16
    unsigned short* Wlo = Whi + 3 * 65536;
    unsigned short* Qh  = Wlo + 3 * 65536;                 // NE u16 (fp16, swizzled)
    unsigned short* Kh  = Qh + NE;                         // NE u16 (fp16)
    unsigned short* Vh  = Kh + NE;                         // NE u16 (fp16)
    float* Lm = (float*)(Vh + NE);                         // NS*4*4096*2 floats

    hipLaunchKernelGGL(prep_kernel, dim3(1027), dim3(256), 0, stream,
                       x, Wq, Wk, Wv, Xhi, Xlo, Whi, Wlo);
    hipLaunchKernelGGL(proj_kernel, dim3(768), dim3(256), 0, stream,
                       Xhi, Xlo, Whi, Wlo, bq, bk, bv, relh, relw, Qh, Kh, Vh);
    if (NS == 4) {
        hipLaunchKernelGGL((flash_kernel<16>), dim3(512), dim3(256), 0, stream,
                           Qh, Kh, Vh, Op, Lm);
        hipLaunchKernelGGL((merge_kernel<4>), dim3(4096), dim3(256), 0, stream,
                           Op, Lm, x, gamma, out);
    } else {
        hipLaunchKernelGGL((flash_kernel<32>), dim3(256), dim3(256), 0, stream,
                           Qh, Kh, Vh, Op, Lm);
        hipLaunchKernelGGL((merge_kernel<2>), dim3(4096), dim3(256), 0, stream,
                           Op, Lm, x, gamma, out);
    }
}